// Round 7
// baseline (52.580 us; speedup 1.0000x reference)
//
#include <hip/hip_runtime.h>
#include <math.h>

// ElasticSparseAttention: B=1, H=16, KVH=4, S=2048, D=64, W=64, layer 12/24.
// One wave per (h,s). Lane (r,c), r=lane>>2, c=lane&3, owns window slot
// j = p*16+r across 4 phases; each quad covers one full 64B line of each
// gathered K/V row. ENFORCED deep prefetch via sched_barrier(0) fences:
// the compiler otherwise sinks the tile loads into consumption order
// (R5 allocated only 36 VGPR -> 8 serialized latency exposures). Fences:
//   issue 16 K loads | fence | dots | issue 16 V loads | fence | softmax
// so each wave has two amortized vmcnt exposures and the softmax DS chain
// hides V latency. All register arrays statically indexed.

#define NH   16
#define SEQ  2048
#define HD   64
#define WIN  64

// Index-math constants folded in double exactly as Python does, then f32.
#define ALPHA_F ((float)(12.0 / 23.0))
#define PD0_F   ((float)(64.0 * (1.0 - 12.0 / 23.0)))
#define NEG_MIN (-3.4028234663852886e38f)

__global__ __launch_bounds__(256, 4) void esa_kernel(
    const float* __restrict__ q,
    const float* __restrict__ k,
    const float* __restrict__ v,
    float* __restrict__ out)
{
    const int lane = threadIdx.x & 63;
    const int wid  = threadIdx.x >> 6;
    const int pair = blockIdx.x * 4 + wid;   // pair = h*SEQ + s
    const int h    = pair >> 11;
    const int s    = pair & (SEQ - 1);
    const int kvh  = h >> 2;

    const int r = lane >> 2;   // window-slot-within-phase 0..15
    const int c = lane & 3;    // 16B chunk within 64B line, 0..3

    // ---- q fragments issued first (independent of index math) ----
    const float4* qrow = (const float4*)(q + (size_t)(h * SEQ + s) * HD);
    float4 qq[4];
    #pragma unroll
    for (int i = 0; i < 4; ++i) qq[i] = qrow[4 * i + c];

    // ---- wave-uniform elastic params (bit-exact f32, no FMA contraction) ----
    const int   end     = (s > WIN - 1) ? s : (WIN - 1);
    const float ids_len = (float)(end + 1);
    const float pd      = __fadd_rn(PD0_F, __fmul_rn(ids_len, ALPHA_F));
    float start_f       = rintf(__fsub_rn(ids_len, pd));
    if (start_f < 0.0f) start_f = 0.0f;
    const int   start   = (int)start_f;
    const float window  = (float)(end + 1 - start);
    const float spacing = __fmul_rn(window, 0.015625f);   // /64 exact
    const float iw      = __fdiv_rn((float)h, 15.0f);
    const float omiw    = __fsub_rn(1.0f, iw);

    // ---- all 4 window indices for this lane's r ----
    int  idxar[4];
    bool valid[4];
    #pragma unroll
    for (int p = 0; p < 4; ++p) {
        const int j    = p * 16 + r;
        const int rel0 = (int)rintf(__fmul_rn((float)j, spacing));
        const int rel1 = (int)rintf(__fmul_rn((float)(j + 1), spacing));
        const int basej    = start + rel0;      // over[:, :W]
        const int shiftedj = start + rel1 - 1;  // over[:, 1:] - 1
        const float idxf = __fadd_rn(__fmul_rn((float)basej, omiw),
                                     __fmul_rn((float)shiftedj, iw));
        int idx = (int)rintf(idxf);
        valid[p] = (idx <= s);
        idxar[p] = valid[p] ? idx : 0;
    }

    const float* kbase = k + (size_t)kvh * SEQ * HD;
    const float* vbase = v + (size_t)kvh * SEQ * HD;

    // ---- issue ALL 16 K-line loads; fence keeps them clustered ----
    float4 kf[4][4];
    #pragma unroll
    for (int p = 0; p < 4; ++p) {
        const float4* krow = (const float4*)(kbase + (size_t)idxar[p] * HD);
        #pragma unroll
        for (int i = 0; i < 4; ++i) kf[p][i] = krow[4 * i + c];
    }
    __builtin_amdgcn_sched_barrier(0);   // forbid sinking K loads into dots

    // ---- dots + quad reduce ----
    float sc[4];
    #pragma unroll
    for (int p = 0; p < 4; ++p) {
        float dot = 0.0f;
        #pragma unroll
        for (int i = 0; i < 4; ++i) {
            dot += qq[i].x * kf[p][i].x + qq[i].y * kf[p][i].y
                 + qq[i].z * kf[p][i].z + qq[i].w * kf[p][i].w;
        }
        dot += __shfl_xor(dot, 1);
        dot += __shfl_xor(dot, 2);
        sc[p] = valid[p] ? dot * 0.125f : NEG_MIN;
    }

    // ---- issue ALL 16 V-line loads BEFORE the softmax chain ----
    float4 vf[4][4];
    #pragma unroll
    for (int p = 0; p < 4; ++p) {
        const float4* vrow = (const float4*)(vbase + (size_t)idxar[p] * HD);
        #pragma unroll
        for (int i = 0; i < 4; ++i) vf[p][i] = vrow[4 * i + c];
    }
    __builtin_amdgcn_sched_barrier(0);   // V stays issued ahead of softmax

    // ---- softmax over 64 slots (values replicated x4 across c) ----
    float m = fmaxf(fmaxf(sc[0], sc[1]), fmaxf(sc[2], sc[3]));
    #pragma unroll
    for (int off = 4; off <= 32; off <<= 1) m = fmaxf(m, __shfl_xor(m, off));
    float e[4];
    float ssum = 0.0f;
    #pragma unroll
    for (int p = 0; p < 4; ++p) { e[p] = __expf(sc[p] - m); ssum += e[p]; }
    #pragma unroll
    for (int off = 4; off <= 32; off <<= 1) ssum += __shfl_xor(ssum, off);

    // ---- PV accumulate (V already resident) ----
    float4 acc[4];
    #pragma unroll
    for (int i = 0; i < 4; ++i) acc[i] = make_float4(0.f, 0.f, 0.f, 0.f);
    #pragma unroll
    for (int p = 0; p < 4; ++p) {
        const float ep = e[p];                  // 0 for masked slots
        #pragma unroll
        for (int i = 0; i < 4; ++i) {
            acc[i].x += ep * vf[p][i].x; acc[i].y += ep * vf[p][i].y;
            acc[i].z += ep * vf[p][i].z; acc[i].w += ep * vf[p][i].w;
        }
    }

    // full reduce across the 16 r-lanes (lane bits 2..5); static indices only
    #pragma unroll
    for (int off = 4; off <= 32; off <<= 1) {
        #pragma unroll
        for (int i = 0; i < 4; ++i) {
            acc[i].x += __shfl_xor(acc[i].x, off);
            acc[i].y += __shfl_xor(acc[i].y, off);
            acc[i].z += __shfl_xor(acc[i].z, off);
            acc[i].w += __shfl_xor(acc[i].w, off);
        }
    }

    // lanes 0..3 (c = lane) each store all 4 chunks at orow[4*i + c]:
    // per i, the 4 lanes' float4s form one contiguous 64B line.
    if (lane < 4) {
        const float inv = 1.0f / ssum;
        float4* orow = (float4*)(out + (size_t)(h * SEQ + s) * HD);
        #pragma unroll
        for (int i = 0; i < 4; ++i) {
            float4 o = acc[i];
            o.x *= inv; o.y *= inv; o.z *= inv; o.w *= inv;
            orow[4 * i + lane] = o;
        }
    }
}

extern "C" void kernel_launch(void* const* d_in, const int* in_sizes, int n_in,
                              void* d_out, int out_size, void* d_ws, size_t ws_size,
                              hipStream_t stream) {
    const float* q = (const float*)d_in[0];
    const float* k = (const float*)d_in[1];
    const float* v = (const float*)d_in[2];
    float* out = (float*)d_out;
    const int nblocks = NH * SEQ / 4;   // 4 waves/block, one (h,s) per wave
    esa_kernel<<<nblocks, 256, 0, stream>>>(q, k, v, out);
}

// Round 8
// 49.382 us; speedup vs baseline: 1.0647x; 1.0647x over previous
//
#include <hip/hip_runtime.h>
#include <math.h>

// ElasticSparseAttention: B=1, H=16, KVH=4, S=2048, D=64, W=64, layer 12/24.
// One wave per (h,s). Lane (r,c), r=lane>>2, c=lane&3, owns window slot
// j = p*16+r across 4 phases; each quad covers one full 64B line of each
// gathered K/V row. MLP is FORCED via volatile inline-asm loads: 16 K-line
// global_load_dwordx4 issued back-to-back (one amortized vmcnt exposure),
// explicit s_waitcnt vmcnt(0) + sched_barrier(0) (compiler hoists register
// consumers past an asm waitcnt otherwise), dots, then 16 V-line loads
// issued BEFORE the softmax shfl chain so V latency hides under it.
// R5/R6 showed the compiler refuses this schedule from plain C (VGPR=36,
// loads sunk into consumption order -> 32 serialized exposures).

#define NH   16
#define SEQ  2048
#define HD   64
#define WIN  64

#define ALPHA_F ((float)(12.0 / 23.0))
#define PD0_F   ((float)(64.0 * (1.0 - 12.0 / 23.0)))
#define NEG_MIN (-3.4028234663852886e38f)

#define GLOAD4(dst, ptr) \
    asm volatile("global_load_dwordx4 %0, %1, off" : "=&v"(dst) : "v"(ptr))

__global__ __launch_bounds__(256, 4) void esa_kernel(
    const float* __restrict__ q,
    const float* __restrict__ k,
    const float* __restrict__ v,
    float* __restrict__ out)
{
    const int lane = threadIdx.x & 63;
    const int wid  = threadIdx.x >> 6;
    const int pair = blockIdx.x * 4 + wid;   // pair = h*SEQ + s
    const int h    = pair >> 11;
    const int s    = pair & (SEQ - 1);
    const int kvh  = h >> 2;

    const int r = lane >> 2;   // window-slot-within-phase 0..15
    const int c = lane & 3;    // 16B chunk within 64B line, 0..3

    // ---- q fragments (compiler loads, issued early; drained with K batch) --
    const float4* qrow = (const float4*)(q + (size_t)(h * SEQ + s) * HD);
    float4 qq[4];
    #pragma unroll
    for (int i = 0; i < 4; ++i) qq[i] = qrow[4 * i + c];

    // ---- wave-uniform elastic params (bit-exact f32, no FMA contraction) ----
    const int   end     = (s > WIN - 1) ? s : (WIN - 1);
    const float ids_len = (float)(end + 1);
    const float pd      = __fadd_rn(PD0_F, __fmul_rn(ids_len, ALPHA_F));
    float start_f       = rintf(__fsub_rn(ids_len, pd));
    if (start_f < 0.0f) start_f = 0.0f;
    const int   start   = (int)start_f;
    const float window  = (float)(end + 1 - start);
    const float spacing = __fmul_rn(window, 0.015625f);   // /64 exact
    const float iw      = __fdiv_rn((float)h, 15.0f);
    const float omiw    = __fsub_rn(1.0f, iw);

    // ---- all 4 window indices for this lane's r ----
    int  idxar[4];
    bool valid[4];
    #pragma unroll
    for (int p = 0; p < 4; ++p) {
        const int j    = p * 16 + r;
        const int rel0 = (int)rintf(__fmul_rn((float)j, spacing));
        const int rel1 = (int)rintf(__fmul_rn((float)(j + 1), spacing));
        const int basej    = start + rel0;      // over[:, :W]
        const int shiftedj = start + rel1 - 1;  // over[:, 1:] - 1
        const float idxf = __fadd_rn(__fmul_rn((float)basej, omiw),
                                     __fmul_rn((float)shiftedj, iw));
        int idx = (int)rintf(idxf);
        valid[p] = (idx <= s);
        idxar[p] = valid[p] ? idx : 0;
    }

    const float* kbase = k + (size_t)kvh * SEQ * HD;
    const float* vbase = v + (size_t)kvh * SEQ * HD;

    // ---- issue ALL 16 K-line loads back-to-back (volatile asm: no sinking) --
    float4 kf[4][4];
    #pragma unroll
    for (int p = 0; p < 4; ++p) {
        const float4* krow = (const float4*)(kbase + (size_t)idxar[p] * HD);
        #pragma unroll
        for (int i = 0; i < 4; ++i) GLOAD4(kf[p][i], krow + 4 * i + c);
    }
    asm volatile("s_waitcnt vmcnt(0)" ::: "memory");  // K (and q) resident
    __builtin_amdgcn_sched_barrier(0);                // nothing hoists above

    // ---- dots + quad reduce ----
    float sc[4];
    #pragma unroll
    for (int p = 0; p < 4; ++p) {
        float dot = 0.0f;
        #pragma unroll
        for (int i = 0; i < 4; ++i) {
            dot += qq[i].x * kf[p][i].x + qq[i].y * kf[p][i].y
                 + qq[i].z * kf[p][i].z + qq[i].w * kf[p][i].w;
        }
        dot += __shfl_xor(dot, 1);
        dot += __shfl_xor(dot, 2);
        sc[p] = valid[p] ? dot * 0.125f : NEG_MIN;
    }

    // ---- issue ALL 16 V-line loads; they fly under the softmax chain ----
    float4 vf[4][4];
    #pragma unroll
    for (int p = 0; p < 4; ++p) {
        const float4* vrow = (const float4*)(vbase + (size_t)idxar[p] * HD);
        #pragma unroll
        for (int i = 0; i < 4; ++i) GLOAD4(vf[p][i], vrow + 4 * i + c);
    }

    // ---- softmax over 64 slots (values replicated x4 across c) ----
    float m = fmaxf(fmaxf(sc[0], sc[1]), fmaxf(sc[2], sc[3]));
    #pragma unroll
    for (int off = 4; off <= 32; off <<= 1) m = fmaxf(m, __shfl_xor(m, off));
    float e[4];
    float ssum = 0.0f;
    #pragma unroll
    for (int p = 0; p < 4; ++p) { e[p] = __expf(sc[p] - m); ssum += e[p]; }
    #pragma unroll
    for (int off = 4; off <= 32; off <<= 1) ssum += __shfl_xor(ssum, off);

    asm volatile("s_waitcnt vmcnt(0)" ::: "memory");  // V resident
    __builtin_amdgcn_sched_barrier(0);

    // ---- PV accumulate (V already resident) ----
    float4 acc[4];
    #pragma unroll
    for (int i = 0; i < 4; ++i) acc[i] = make_float4(0.f, 0.f, 0.f, 0.f);
    #pragma unroll
    for (int p = 0; p < 4; ++p) {
        const float ep = e[p];                  // 0 for masked slots
        #pragma unroll
        for (int i = 0; i < 4; ++i) {
            acc[i].x += ep * vf[p][i].x; acc[i].y += ep * vf[p][i].y;
            acc[i].z += ep * vf[p][i].z; acc[i].w += ep * vf[p][i].w;
        }
    }

    // full reduce across the 16 r-lanes (lane bits 2..5); static indices only
    #pragma unroll
    for (int off = 4; off <= 32; off <<= 1) {
        #pragma unroll
        for (int i = 0; i < 4; ++i) {
            acc[i].x += __shfl_xor(acc[i].x, off);
            acc[i].y += __shfl_xor(acc[i].y, off);
            acc[i].z += __shfl_xor(acc[i].z, off);
            acc[i].w += __shfl_xor(acc[i].w, off);
        }
    }

    // lanes 0..3 (c = lane) each store all 4 chunks at orow[4*i + c]:
    // per i, the 4 lanes' float4s form one contiguous 64B line.
    if (lane < 4) {
        const float inv = 1.0f / ssum;
        float4* orow = (float4*)(out + (size_t)(h * SEQ + s) * HD);
        #pragma unroll
        for (int i = 0; i < 4; ++i) {
            float4 o = acc[i];
            o.x *= inv; o.y *= inv; o.z *= inv; o.w *= inv;
            orow[4 * i + lane] = o;
        }
    }
}

extern "C" void kernel_launch(void* const* d_in, const int* in_sizes, int n_in,
                              void* d_out, int out_size, void* d_ws, size_t ws_size,
                              hipStream_t stream) {
    const float* q = (const float*)d_in[0];
    const float* k = (const float*)d_in[1];
    const float* v = (const float*)d_in[2];
    float* out = (float*)d_out;
    const int nblocks = NH * SEQ / 4;   // 4 waves/block, one (h,s) per wave
    esa_kernel<<<nblocks, 256, 0, stream>>>(q, k, v, out);
}

// Round 9
// 41.186 us; speedup vs baseline: 1.2766x; 1.1990x over previous
//
#include <hip/hip_runtime.h>
#include <math.h>

// ElasticSparseAttention: B=1, H=16, KVH=4, S=2048, D=64, W=64, layer 12/24.
// Best-measured structure (R1, 46.9us): quad-coalesced QK + readlane-PV.
// This round adds locality: 512-thread blocks (8 waves = 8 CONSECUTIVE s of
// one head -> overlapping windows share L1 lines within the CU) and an
// XCD-contiguous block remap (block b -> XCD b%8 by hardware round-robin;
// remapped so each XCD owns pairs [x*4096,(x+1)*4096) = heads {2x,2x+1} =
// ONE kv-head -> its 1MB K+V slice + 1MB q slice stay resident in that
// XCD's 4MB L2). PV uses 4 independent fmac chains. No register tiles, no
// launch-bounds cap: VGPR ~40 keeps ~8 waves/SIMD of TLP for latency hiding.

#define NH   16
#define SEQ  2048
#define HD   64
#define WIN  64

// Index-math constants folded in double exactly as Python does, then f32.
#define ALPHA_F ((float)(12.0 / 23.0))
#define PD0_F   ((float)(64.0 * (1.0 - 12.0 / 23.0)))
#define NEG_MIN (-3.4028234663852886e38f)

__global__ __launch_bounds__(512) void esa_kernel(
    const float* __restrict__ q,
    const float* __restrict__ k,
    const float* __restrict__ v,
    float* __restrict__ out)
{
    const int lane = threadIdx.x & 63;
    const int wid  = threadIdx.x >> 6;          // 0..7

    // XCD-contiguous remap: 4096 blocks, hardware XCD = blockIdx.x % 8.
    // chunk = xcd*512 + slot  ->  XCD x executes pairs [x*4096,(x+1)*4096).
    const int xcd  = blockIdx.x & 7;
    const int slot = blockIdx.x >> 3;
    const int pair = (xcd * 512 + slot) * 8 + wid;   // = h*SEQ + s
    const int h    = pair >> 11;
    const int s    = pair & (SEQ - 1);
    const int kvh  = h >> 2;

    const int r = lane >> 2;   // window-slot-within-phase 0..15
    const int c = lane & 3;    // 16B chunk within 64B line, 0..3

    // ---- q fragments straight from global (4 broadcast-line loads) ----
    const float4* qrow = (const float4*)(q + (size_t)(h * SEQ + s) * HD);
    float4 qq[4];
    #pragma unroll
    for (int i = 0; i < 4; ++i) qq[i] = qrow[4 * i + c];

    // ---- wave-uniform elastic params (bit-exact f32, no FMA contraction) ----
    const int   end     = (s > WIN - 1) ? s : (WIN - 1);
    const float ids_len = (float)(end + 1);
    const float pd      = __fadd_rn(PD0_F, __fmul_rn(ids_len, ALPHA_F));
    float start_f       = rintf(__fsub_rn(ids_len, pd));
    if (start_f < 0.0f) start_f = 0.0f;
    const int   start   = (int)start_f;
    const float window  = (float)(end + 1 - start);
    const float spacing = __fmul_rn(window, 0.015625f);   // /64 exact
    const float iw      = __fdiv_rn((float)h, 15.0f);
    const float omiw    = __fsub_rn(1.0f, iw);

    const float* kbase = k + (size_t)kvh * SEQ * HD;
    const float* vbase = v + (size_t)kvh * SEQ * HD;

    // ---- QK: 4 phases x 16 rows; quad-per-row fully-coalesced gather ----
    float sc[4];
    int   idxar[4];
    #pragma unroll
    for (int p = 0; p < 4; ++p) {
        const int j    = p * 16 + r;
        const int rel0 = (int)rintf(__fmul_rn((float)j, spacing));
        const int rel1 = (int)rintf(__fmul_rn((float)(j + 1), spacing));
        const int basej    = start + rel0;      // over[:, :W]
        const int shiftedj = start + rel1 - 1;  // over[:, 1:] - 1
        const float idxf = __fadd_rn(__fmul_rn((float)basej, omiw),
                                     __fmul_rn((float)shiftedj, iw));
        int idx = (int)rintf(idxf);
        const bool valid = (idx <= s);
        if (!valid) idx = 0;
        idxar[p] = idx;

        const float4* krow = (const float4*)(kbase + (size_t)idx * HD);
        float dot = 0.0f;
        #pragma unroll
        for (int i = 0; i < 4; ++i) {
            float4 kk = krow[4 * i + c];
            dot += qq[i].x * kk.x + qq[i].y * kk.y
                 + qq[i].z * kk.z + qq[i].w * kk.w;
        }
        dot += __shfl_xor(dot, 1);              // reduce across the quad
        dot += __shfl_xor(dot, 2);
        sc[p] = valid ? dot * 0.125f : NEG_MIN;
    }

    // ---- softmax over 64 slots (values replicated x4 across c) ----
    float m = fmaxf(fmaxf(sc[0], sc[1]), fmaxf(sc[2], sc[3]));
    #pragma unroll
    for (int off = 4; off <= 32; off <<= 1) m = fmaxf(m, __shfl_xor(m, off));
    float e[4];
    float ssum = 0.0f;
    #pragma unroll
    for (int p = 0; p < 4; ++p) { e[p] = __expf(sc[p] - m); ssum += e[p]; }
    #pragma unroll
    for (int off = 4; off <= 32; off <<= 1) ssum += __shfl_xor(ssum, off);

    // ---- PV: lanes switch to dimension d; serial j with scalar broadcast.
    // slot j lives at lanes (j&15)*4 + c, array element j>>4 (both static
    // per unrolled iteration -> no scratch). 4 independent fmac chains.
    const float* vcol = vbase + lane;
    float o0 = 0.0f, o1 = 0.0f, o2 = 0.0f, o3 = 0.0f;
    #pragma unroll
    for (int jj = 0; jj < WIN; ++jj) {
        const int   ij = __builtin_amdgcn_readlane(idxar[jj >> 4], (jj & 15) * 4);
        const float pj = __uint_as_float(
            __builtin_amdgcn_readlane(__float_as_uint(e[jj >> 4]), (jj & 15) * 4));
        const float val = pj * vcol[(size_t)ij * HD];
        if      ((jj & 3) == 0) o0 += val;
        else if ((jj & 3) == 1) o1 += val;
        else if ((jj & 3) == 2) o2 += val;
        else                    o3 += val;
    }
    out[(size_t)(h * SEQ + s) * HD + lane] = ((o0 + o1) + (o2 + o3)) / ssum;
}

extern "C" void kernel_launch(void* const* d_in, const int* in_sizes, int n_in,
                              void* d_out, int out_size, void* d_ws, size_t ws_size,
                              hipStream_t stream) {
    const float* q = (const float*)d_in[0];
    const float* k = (const float*)d_in[1];
    const float* v = (const float*)d_in[2];
    float* out = (float*)d_out;
    const int nblocks = NH * SEQ / 8;   // 4096 blocks x 8 waves (512 thr)
    esa_kernel<<<nblocks, 512, 0, stream>>>(q, k, v, out);
}